// Round 5
// baseline (173.551 us; speedup 1.0000x reference)
//
#include <hip/hip_runtime.h>
#include <hip/hip_bf16.h>

typedef short bf16x8 __attribute__((ext_vector_type(8)));
typedef unsigned short u16x8 __attribute__((ext_vector_type(8)));
typedef float f32x4 __attribute__((ext_vector_type(4)));

#define LQ 300
#define LV 21760
#define NQ 2400   // bs * LQ

__device__ __forceinline__ unsigned short f2bf(float x) {   // HW RNE convert
    __hip_bfloat16 h = __float2bfloat16(x);
    return *reinterpret_cast<unsigned short*>(&h);
}
__device__ __forceinline__ float bf2f(unsigned short s) {
    return __uint_as_float(((unsigned)s) << 16);
}
__device__ __forceinline__ bf16x8 cvt8(float4 a, float4 b) {
    u16x8 u;
    u[0] = f2bf(a.x); u[1] = f2bf(a.y); u[2] = f2bf(a.z); u[3] = f2bf(a.w);
    u[4] = f2bf(b.x); u[5] = f2bf(b.y); u[6] = f2bf(b.z); u[7] = f2bf(b.w);
    return (bf16x8)u;
}

// ---------------------------------------------------------------- K1: transpose+convert all weights to bf16 [n][k]
__global__ void k_wt(const float* __restrict__ Wv, const float* __restrict__ Woff,
                     const float* __restrict__ Wattn, const float* __restrict__ Wout,
                     unsigned short* __restrict__ ws) {
    int i = blockIdx.x * 256 + threadIdx.x;   // 229376 total
    if (i < 65536) {
        int n = i >> 8, k = i & 255;
        ws[i] = f2bf(Wv[k * 256 + n]);
    } else if (i < 65536 + 98304) {
        int j = i - 65536;
        int n = j >> 8, k = j & 255;
        float s = (n < 256) ? Woff[k * 256 + n] : Wattn[k * 128 + (n - 256)];
        ws[i] = f2bf(s);
    } else {
        int j = i - 163840;
        int n = j >> 8, k = j & 255;
        ws[i] = f2bf(Wout[k * 256 + n]);
    }
}

// ---------------------------------------------------------------- K2: v = value @ W_value + b  (M=174080,N=256,K=256)
// BM=64, 256 thr = 4 waves (wave = B col-group). A staged as f32 via async
// global_load_lds (one instr per row, all in flight, no VGPR round-trip);
// f32->bf16 at frag read via v_cvt. Epilogue reuses LDS for coalesced C.
__global__ __launch_bounds__(256, 2) void k_vproj(
    const float* __restrict__ A, const unsigned short* __restrict__ Bt,
    const float* __restrict__ bias, unsigned short* __restrict__ C)
{
    __shared__ union {
        float a[64][260];            // +4 f32 pad: ds_read_b128 at bank floor
        unsigned short c[64][264];
    } sm;
    const int t = threadIdx.x;
    const int lane = t & 63;
    const int wv = t >> 6;           // wave id == B col group
    const int fr = lane & 15, kg = lane >> 4;
    const size_t rowBase = (size_t)blockIdx.x * 64;
    const float* abase = A + rowBase * 256;

    // ---- async stage: 16 rows/wave, 1 KB per instr, linear LDS dest (pad skipped per-row)
#pragma unroll
    for (int i = 0; i < 16; ++i) {
        const int r = wv * 16 + i;
        __builtin_amdgcn_global_load_lds(
            (const __attribute__((address_space(1))) void*)(abase + (size_t)r * 256 + lane * 4),
            (__attribute__((address_space(3))) void*)&sm.a[r][0], 16, 0, 0);
    }

    f32x4 acc[4][4];
#pragma unroll
    for (int m = 0; m < 4; m++)
#pragma unroll
        for (int n = 0; n < 4; n++) { f32x4 z = {0.f, 0.f, 0.f, 0.f}; acc[m][n] = z; }

    __syncthreads();   // drains vmcnt (global_load_lds) before LDS reads

    // ---- barrier-free MFMA loop; B frags stream from L2-hot 128 KB Wt
#pragma unroll
    for (int kk = 0; kk < 8; ++kk) {
        bf16x8 a[4], bb[4];
#pragma unroll
        for (int n = 0; n < 4; ++n)
            bb[n] = *(const bf16x8*)(Bt + (size_t)(wv * 64 + n * 16 + fr) * 256 + kk * 32 + kg * 8);
#pragma unroll
        for (int m = 0; m < 4; ++m) {
            const float* ap = &sm.a[m * 16 + fr][kk * 32 + kg * 8];
            float4 af0 = *(const float4*)ap;
            float4 af1 = *(const float4*)(ap + 4);
            a[m] = cvt8(af0, af1);
        }
#pragma unroll
        for (int m = 0; m < 4; ++m)
#pragma unroll
            for (int n = 0; n < 4; ++n)
                acc[m][n] = __builtin_amdgcn_mfma_f32_16x16x32_bf16(a[m], bb[n], acc[m][n], 0, 0, 0);
    }

    // ---- epilogue: C tile -> LDS (bf16) -> 16 B/lane coalesced stores
    __syncthreads();
#pragma unroll
    for (int n = 0; n < 4; ++n) {
        int col = wv * 64 + n * 16 + fr;
        float bv = bias[col];
#pragma unroll
        for (int m = 0; m < 4; ++m)
#pragma unroll
            for (int r = 0; r < 4; ++r)
                sm.c[m * 16 + kg * 4 + r][col] = f2bf(acc[m][n][r] + bv);
    }
    __syncthreads();
    unsigned short* cbase = C + rowBase * 256;
#pragma unroll
    for (int i = 0; i < 8; ++i) {
        int e = (i * 256 + t) * 8;
        *(u16x8*)(cbase + e) = *(const u16x8*)&sm.c[e >> 8][e & 255];
    }
}

// ---------------------------------------------------------------- K3: [off|attn] = query @ [W_off|W_attn] + bias
__global__ __launch_bounds__(512) void k_qproj(
    const float* __restrict__ Q, const unsigned short* __restrict__ Woa,
    const float* __restrict__ b_off, const float* __restrict__ b_attn,
    float* __restrict__ offattn)
{
    const int t = threadIdx.x;
    const int lane = t & 63;
    const int wid = t >> 6;
    const int wr = wid >> 2, wc = wid & 3;
    const int fr = lane & 15, kg = lane >> 4;
    const int rowBase = blockIdx.x * 64;

    const int r0 = min(rowBase + wr * 32 + fr, NQ - 1);
    const int r1 = min(rowBase + wr * 32 + 16 + fr, NQ - 1);

    f32x4 acc[2][6];
#pragma unroll
    for (int m = 0; m < 2; m++)
#pragma unroll
        for (int n = 0; n < 6; n++) { f32x4 z = {0.f, 0.f, 0.f, 0.f}; acc[m][n] = z; }

#pragma unroll
    for (int kk = 0; kk < 8; ++kk) {
        const int kb = kk * 32 + kg * 8;
        float4 q00 = *(const float4*)(Q + (size_t)r0 * 256 + kb);
        float4 q01 = *(const float4*)(Q + (size_t)r0 * 256 + kb + 4);
        float4 q10 = *(const float4*)(Q + (size_t)r1 * 256 + kb);
        float4 q11 = *(const float4*)(Q + (size_t)r1 * 256 + kb + 4);
        bf16x8 a0 = cvt8(q00, q01);
        bf16x8 a1 = cvt8(q10, q11);
#pragma unroll
        for (int n = 0; n < 6; n++) {
            bf16x8 bb = *(const bf16x8*)(Woa + (size_t)(wc * 96 + n * 16 + fr) * 256 + kb);
            acc[0][n] = __builtin_amdgcn_mfma_f32_16x16x32_bf16(a0, bb, acc[0][n], 0, 0, 0);
            acc[1][n] = __builtin_amdgcn_mfma_f32_16x16x32_bf16(a1, bb, acc[1][n], 0, 0, 0);
        }
    }

#pragma unroll
    for (int m = 0; m < 2; m++) {
#pragma unroll
        for (int n = 0; n < 6; n++) {
            int col = wc * 96 + n * 16 + fr;
            float bv = (col < 256) ? b_off[col] : b_attn[col - 256];
#pragma unroll
            for (int r = 0; r < 4; r++) {
                int row = rowBase + wr * 32 + m * 16 + kg * 4 + r;
                if (row < NQ) offattn[(size_t)row * 384 + col] = acc[m][n][r] + bv;
            }
        }
    }
}

// ---------------------------------------------------------------- K4: softmax + grid + bilinear gather. 1 block = 1 query.
__global__ __launch_bounds__(256) void k_sample(
    const float* __restrict__ refp, const float* __restrict__ offattn,
    const unsigned short* __restrict__ V, unsigned short* __restrict__ att)
{
    __shared__ float aw[128], gx[128], gy[128];
    const int t = threadIdx.x;
    const int row = blockIdx.x;          // global query index
    const int b = row / LQ;
    const float* oa = offattn + (size_t)row * 384;

    if (t < 128) {
        float logit = oa[256 + t];
        float m = logit;
        m = fmaxf(m, __shfl_xor(m, 1));
        m = fmaxf(m, __shfl_xor(m, 2));
        m = fmaxf(m, __shfl_xor(m, 4));
        m = fmaxf(m, __shfl_xor(m, 8));
        float e = __expf(logit - m);
        float s = e;
        s += __shfl_xor(s, 1);
        s += __shfl_xor(s, 2);
        s += __shfl_xor(s, 4);
        s += __shfl_xor(s, 8);
        aw[t] = e / s;
        const int l = (t >> 2) & 3;
        const float Wl = (l == 0) ? 128.f : (l == 1) ? 64.f : (l == 2) ? 32.f : 16.f;
        float ox = oa[2 * t], oy = oa[2 * t + 1];
        const float* rp = refp + ((size_t)row * 4 + l) * 4;
        gx[t] = (rp[0] + ox * 0.125f * rp[2]) * Wl - 0.5f;
        gy[t] = (rp[1] + oy * 0.125f * rp[3]) * Wl - 0.5f;
    }
    __syncthreads();

    const int h = t >> 5;
    float acc = 0.f;
#pragma unroll 4
    for (int jj = 0; jj < 16; jj++) {
        const int l = jj >> 2;
        const int Wl = (l == 0) ? 128 : (l == 1) ? 64 : (l == 2) ? 32 : 16;
        const int S  = (l == 0) ? 0 : (l == 1) ? 16384 : (l == 2) ? 20480 : 21504;
        int pt = h * 16 + jj;
        float a  = aw[pt];
        float sx = gx[pt], sy = gy[pt];
        float x0f = floorf(sx), y0f = floorf(sy);
        int   x0 = (int)x0f, y0 = (int)y0f;
        float wx1 = sx - x0f, wy1 = sy - y0f;
        float wx0 = 1.f - wx1, wy0 = 1.f - wy1;
        bool vx0 = (unsigned)x0 < (unsigned)Wl;
        bool vx1 = (unsigned)(x0 + 1) < (unsigned)Wl;
        bool vy0 = (unsigned)y0 < (unsigned)Wl;
        bool vy1 = (unsigned)(y0 + 1) < (unsigned)Wl;
        float v00 = 0.f, v01 = 0.f, v10 = 0.f, v11 = 0.f;
        size_t pixBase = (size_t)b * LV + S;
        if (vy0) {
            size_t rb = (pixBase + (size_t)y0 * Wl) * 256 + t;
            if (vx0) v00 = bf2f(V[rb + (size_t)x0 * 256]);
            if (vx1) v01 = bf2f(V[rb + (size_t)x0 * 256 + 256]);
        }
        if (vy1) {
            size_t rb = (pixBase + (size_t)(y0 + 1) * Wl) * 256 + t;
            if (vx0) v10 = bf2f(V[rb + (size_t)x0 * 256]);
            if (vx1) v11 = bf2f(V[rb + (size_t)x0 * 256 + 256]);
        }
        acc += a * (wy0 * (wx0 * v00 + wx1 * v01) + wy1 * (wx0 * v10 + wx1 * v11));
    }
    att[(size_t)row * 256 + t] = f2bf(acc);
}

// ---------------------------------------------------------------- K5: out = att @ W_out + b_out (M=2400,N=256,K=256)
__global__ __launch_bounds__(256) void k_outproj(
    const unsigned short* __restrict__ att, const unsigned short* __restrict__ Wout,
    const float* __restrict__ b_out, float* __restrict__ out)
{
    const int t = threadIdx.x;
    const int lane = t & 63;
    const int wc = t >> 6;
    const int fr = lane & 15, kg = lane >> 4;
    const int rowBase = blockIdx.x * 64;

    f32x4 acc[4][4];
#pragma unroll
    for (int m = 0; m < 4; m++)
#pragma unroll
        for (int n = 0; n < 4; n++) { f32x4 z = {0.f, 0.f, 0.f, 0.f}; acc[m][n] = z; }

#pragma unroll
    for (int kk = 0; kk < 8; ++kk) {
        const int kb = kk * 32 + kg * 8;
        bf16x8 a[4], bb[4];
#pragma unroll
        for (int m = 0; m < 4; m++) {
            int row = min(rowBase + m * 16 + fr, NQ - 1);
            a[m] = *(const bf16x8*)(att + (size_t)row * 256 + kb);
        }
#pragma unroll
        for (int n = 0; n < 4; n++)
            bb[n] = *(const bf16x8*)(Wout + (size_t)(wc * 64 + n * 16 + fr) * 256 + kb);
#pragma unroll
        for (int m = 0; m < 4; m++)
#pragma unroll
            for (int n = 0; n < 4; n++)
                acc[m][n] = __builtin_amdgcn_mfma_f32_16x16x32_bf16(a[m], bb[n], acc[m][n], 0, 0, 0);
    }

#pragma unroll
    for (int m = 0; m < 4; m++) {
#pragma unroll
        for (int n = 0; n < 4; n++) {
            int col = wc * 64 + n * 16 + fr;
            float bv = b_out[col];
#pragma unroll
            for (int r = 0; r < 4; r++) {
                int row = rowBase + m * 16 + kg * 4 + r;
                if (row < NQ) out[(size_t)row * 256 + col] = acc[m][n][r] + bv;
            }
        }
    }
}

// ----------------------------------------------------------------
extern "C" void kernel_launch(void* const* d_in, const int* in_sizes, int n_in,
                              void* d_out, int out_size, void* d_ws, size_t ws_size,
                              hipStream_t stream) {
    const float* query   = (const float*)d_in[0];
    const float* refp    = (const float*)d_in[1];
    const float* value   = (const float*)d_in[2];
    const float* W_value = (const float*)d_in[3];
    const float* b_value = (const float*)d_in[4];
    const float* W_off   = (const float*)d_in[5];
    const float* b_off   = (const float*)d_in[6];
    const float* W_attn  = (const float*)d_in[7];
    const float* b_attn  = (const float*)d_in[8];
    const float* W_out   = (const float*)d_in[9];
    const float* b_out   = (const float*)d_in[10];
    float* out = (float*)d_out;

    unsigned short* wsu   = (unsigned short*)d_ws;
    unsigned short* Wt_v  = wsu;                       // 65536
    unsigned short* Wt_oa = Wt_v + 65536;              // 98304
    unsigned short* Wt_out= Wt_oa + 98304;             // 65536
    unsigned short* V     = Wt_out + 65536;            // 174080*256
    float* offattn = (float*)(V + (size_t)174080 * 256);   // 2400*384 f32
    unsigned short* att = (unsigned short*)(offattn + (size_t)NQ * 384); // 2400*256 bf16

    k_wt<<<896, 256, 0, stream>>>(W_value, W_off, W_attn, W_out, wsu);
    k_qproj<<<38, 512, 0, stream>>>(query, Wt_oa, b_off, b_attn, offattn);
    k_vproj<<<2720, 256, 0, stream>>>(value, Wt_v, b_value, V);
    k_sample<<<NQ, 256, 0, stream>>>(refp, offattn, V, att);
    k_outproj<<<38, 256, 0, stream>>>(att, Wt_out, b_out, out);
}